// Round 8
// baseline (108.127 us; speedup 1.0000x reference)
//
#include <hip/hip_runtime.h>
#include <hip/hip_bf16.h>
#include <stdint.h>

typedef short bf16x8 __attribute__((ext_vector_type(8)));
typedef short bf16x4 __attribute__((ext_vector_type(4)));
typedef float f32x4 __attribute__((ext_vector_type(4)));

#define NN 4096

static __device__ __forceinline__ short f2b(float f) {
    union { float f; uint32_t u; } a; a.f = f;
    uint32_t r = a.u + 0x7FFFu + ((a.u >> 16) & 1u);
    return (short)(r >> 16);
}

// ---- output region offsets (in floats) ----
#define OFF_QMV   0UL
#define OFF_KMV   8388608UL
#define OFF_VMV   16777216UL
#define OFF_VMVQ  25165824UL
#define OFF_QS    33554432UL
#define OFF_KS    35651584UL
#define OFF_VS    37748736UL
#define OFF_VSQ   39845888UL

// ---- ws layout (bf16 elements) ----
#define WS_BMV_END   73728
#define WS_SW_BASE   106496
#define WS_TS_BASE   270336
#define WS_PACK_END  1318912
#define WS_TIN_BASE  1318912
#define WS_TOTAL     5513216   // shorts -> 11,026,432 bytes of scratch

// MV-GEMM column-channel map: (ct, lane) -> output channel O in [0,128)
static __device__ __forceinline__ int mv_chan(int ct, int l) {
    return (ct >> 2) * 64 + (l & 7) * 8 + (ct & 3) * 2 + ((l >> 3) & 1);
}

// col-channel mapping for the S GEMM: o(ct,lr) — bijective, bit-disjoint
static __device__ __forceinline__ int s_chan(int ct, int lr) {
    int hid = (ct & 3) + 4 * (lr >> 3) + 8 * (ct >> 2);
    return (lr & 7) + 8 * hid;
}

// ============ prep: vectorized copies + weight packs ========================
__global__ __launch_bounds__(256) void prep_all(
    const float* __restrict__ inputs, const float* __restrict__ scalars,
    const float* __restrict__ qwmv,   const float* __restrict__ qws2mv,
    const float* __restrict__ qwmv2s, const float* __restrict__ qws2s,
    const float* __restrict__ kvwmv,  const float* __restrict__ kvws2mv,
    const float* __restrict__ kvwmv2s,const float* __restrict__ kvws2s,
    short* __restrict__ ws)
{
    if (blockIdx.x < 128) {
        const int t  = blockIdx.x * 256 + threadIdx.x;   // 32768
        const int xg = t & 3;
        const int bn = t >> 2;
        const float* src = inputs + (size_t)bn * 512 + xg * 4;
        short tmp[4][32];
        #pragma unroll
        for (int i = 0; i < 32; ++i) {
            const float4 v = *(const float4*)(src + i * 16);
            tmp[0][i] = f2b(v.x); tmp[1][i] = f2b(v.y);
            tmp[2][i] = f2b(v.z); tmp[3][i] = f2b(v.w);
        }
        short* dst = ws + WS_TIN_BASE + (size_t)bn * 512 + xg * 128;
        #pragma unroll
        for (int r = 0; r < 4; ++r)
            #pragma unroll
            for (int j = 0; j < 4; ++j)
                *(bf16x8*)(dst + r * 32 + j * 8) = *(const bf16x8*)(&tmp[r][j * 8]);
        return;
    }
    if (blockIdx.x < 1152) {
        const int id = (blockIdx.x - 128) * 256 + threadIdx.x;   // [0, 262144)
        const float4 v = *(const float4*)(scalars + (size_t)id * 4);
        bf16x4 o = {f2b(v.x), f2b(v.y), f2b(v.z), f2b(v.w)};
        *(bf16x4*)(ws + WS_TS_BASE + (size_t)id * 4) = o;
        return;
    }
    const int id = (blockIdx.x - 1152) * 256 + threadIdx.x;
    if (id >= WS_TS_BASE) return;
    float v;
    if (id < WS_BMV_END) {
        int rem = id; int task = rem / 36864; rem -= task * 36864;
        int y = rem / 4096; rem -= y * 4096;
        int ct = rem >> 9; int l = (rem >> 3) & 63; int e = rem & 7;
        int o = mv_chan(ct, l);
        int i = (l >> 4) * 8 + e;
        const float* w = (task == 0 || o >= 64) ? kvwmv : qwmv;
        v = w[(o * 32 + i) * 9 + y];
    } else if (id < WS_SW_BASE) {
        int rem = id - WS_BMV_END; int task = rem / 16384; rem -= task * 16384;
        int kk = rem / 4096; rem -= kk * 4096;
        int ct = rem >> 9; int l = (rem >> 3) & 63; int e = rem & 7;
        int o = mv_chan(ct, l);
        int k = kk * 32 + (l >> 4) * 8 + e;
        const float* w = (task == 0 || o >= 64) ? kvws2mv : qws2mv;
        v = w[o * 128 + k];
    } else {
        int rem = id - WS_SW_BASE; int task = rem / 81920; rem -= task * 81920;
        int ct = rem / 2560; rem -= ct * 2560;
        int lr = rem / 160;  int k = rem - lr * 160;
        int o = s_chan(ct, lr);
        if (k < 32) {
            const float* w = (task == 0 || o >= 256) ? kvwmv2s : qwmv2s;
            v = w[o * 32 + k];
        } else {
            const float* w = (task == 0 || o >= 256) ? kvws2s : qws2s;
            v = w[o * 128 + (k - 32)];
        }
    }
    ws[id] = f2b(v);
}

// ========== fused MV + S outputs: LDS-transpose + nontemporal stores ========
__global__ __launch_bounds__(256) void fused_all(
    const float* __restrict__ q_b_s,  const float* __restrict__ kv_b_s,
    const int* __restrict__ q_idx,    const int* __restrict__ kv_idx,
    const short* __restrict__ ws,     float* __restrict__ out)
{
    const int GR[16]   = {0,1,1,1,1,2,2,2,2,2,2,3,3,3,3,4};
    const int SRC[16]  = {-1,0,-1,-1,-1,2,3,4,-1,-1,-1,8,9,10,-1,14};
    const int EMAP[16] = {0,5,0,0,0,6,6,6,0,0,0,7,7,7,0,8};

    __shared__ __align__(16) char SMEM[65536];
    short* XA = (short*)SMEM;            // [r:16][x:16][i:32], row stride 520
    short* XS = XA + 16 * 520;           // [r:16][k:128], stride 136

    const int tid  = threadIdx.x;
    const int bid  = blockIdx.x;
    const int tile = bid & 255;
    const int b    = (bid >> 8) & 1;
    const int task = bid >> 9;          // 0 = kv-task, 1 = q-task
    const int n0   = tile * 16;
    const int* ridx = task ? q_idx : kv_idx;

    {
        const int r = tid >> 4, c = tid & 15;
        const int m = ridx[n0 + r];
        const short* srcA = ws + WS_TIN_BASE + (size_t)(b * NN + m) * 512 + c * 32;
        #pragma unroll
        for (int j = 0; j < 4; ++j)
            *(bf16x8*)(XA + r * 520 + c * 32 + j * 8) = *(const bf16x8*)(srcA + j * 8);
        const short* srcS = ws + WS_TS_BASE + (size_t)(b * NN + m) * 128 + c * 8;
        *(bf16x8*)(XS + r * 136 + c * 8) = *(const bf16x8*)(srcS);
    }
    __syncthreads();

    const int w  = tid >> 6;
    const int l  = tid & 63;
    const int lr = l & 15;
    const int lg = l >> 4;

    bf16x8 Ax[16];
    #pragma unroll
    for (int x = 0; x < 16; ++x)
        Ax[x] = *(const bf16x8*)(XA + lr * 520 + x * 32 + lg * 8);
    bf16x8 Sx[4];
    #pragma unroll
    for (int kk = 0; kk < 4; ++kk)
        Sx[kk] = *(const bf16x8*)(XS + lr * 136 + kk * 32 + lg * 8);
    __syncthreads();   // XA/XS dead; SMEM becomes per-wave mv-OUT buffers

    float* OUTw = (float*)SMEM + w * 4096;   // [row:32][128 floats], 16 KB/wave

    // ================= MV phase =================
    #pragma unroll
    for (int cc = 0; cc < 2; ++cc) {
        const int ct = 2 * w + cc;
        bf16x8 Bg[9];
        #pragma unroll
        for (int y = 0; y < 9; ++y)
            Bg[y] = *(const bf16x8*)(ws + ((((size_t)task * 9 + y) * 8 + ct) * 64 + l) * 8);

        #pragma unroll
        for (int xc = 0; xc < 4; ++xc) {
            f32x4 acc[4];
            #pragma unroll
            for (int q = 0; q < 4; ++q) {
                const int x = xc * 4 + q;
                f32x4 a0 = {0.f, 0.f, 0.f, 0.f};
                a0 = __builtin_amdgcn_mfma_f32_16x16x32_bf16(Ax[x], Bg[GR[x]], a0, 0, 0, 0);
                if (SRC[x] >= 0)
                    a0 = __builtin_amdgcn_mfma_f32_16x16x32_bf16(Ax[SRC[x]], Bg[EMAP[x]], a0, 0, 0, 0);
                if (x == 0) {
                    #pragma unroll
                    for (int kk = 0; kk < 4; ++kk) {
                        bf16x8 bs2 = *(const bf16x8*)(ws + WS_BMV_END +
                                       ((((size_t)task * 4 + kk) * 8 + ct) * 64 + l) * 8);
                        a0 = __builtin_amdgcn_mfma_f32_16x16x32_bf16(Sx[kk], bs2, a0, 0, 0, 0);
                    }
                }
                acc[q] = a0;
            }
            #pragma unroll
            for (int j = 0; j < 4; ++j) {
                const int roww = (lr >> 3) * 16 + lg * 4 + j;
                const int cqw  = ((lr & 7) * 4 + xc) ^ ((roww >> 2) & 7);
                *(f32x4*)(OUTw + roww * 128 + cqw * 4) =
                    (f32x4){acc[0][j], acc[1][j], acc[2][j], acc[3][j]};
            }
        }

        const int region = ct >> 2;
        const size_t obase = task ? (region ? OFF_VMVQ : OFF_QMV)
                                  : (region ? OFF_VMV  : OFF_KMV);
        #pragma unroll
        for (int t = 0; t < 16; ++t) {
            const int row  = 2 * t + (l >> 5);
            const int h2   = row >> 4, nl = row & 15;
            const int head = (ct & 3) * 2 + h2;
            const int cq   = (l & 31) ^ ((row >> 2) & 7);
            f32x4 v = *(const f32x4*)(OUTw + row * 128 + cq * 4);
            __builtin_nontemporal_store(v,
                (f32x4*)(out + obase + (((size_t)(b * 8 + head)) * NN + n0 + nl) * 128
                         + (l & 31) * 4));
        }
    }

    // ================= S phase (reuses Ax[0], Sx in registers) =================
    __syncthreads();                       // mv-OUT dead in all waves
    float* OUTS = (float*)SMEM;            // [R:256][32 floats], 32 KB

    #pragma unroll
    for (int q8 = 0; q8 < 2; ++q8) {
        const int hidbase = 16 * w + 8 * q8 + 4 * (lr >> 3);
        const int head    = lr & 7;
        const int hq      = hidbase >> 2;          // global hid-quad
        const int region  = w >> 1;
        f32x4 acc4[4];
        #pragma unroll
        for (int jj = 0; jj < 4; ++jj) {
            const int ct = w * 8 + q8 * 4 + jj;
            const short* bp = ws + WS_SW_BASE +
                              (((size_t)task * 32 + ct) * 16 + lr) * 160 + lg * 8;
            f32x4 acc = {0.f, 0.f, 0.f, 0.f};
            acc = __builtin_amdgcn_mfma_f32_16x16x32_bf16(Ax[0], *(const bf16x8*)bp, acc, 0, 0, 0);
            #pragma unroll
            for (int c = 0; c < 4; ++c)
                acc = __builtin_amdgcn_mfma_f32_16x16x32_bf16(
                          Sx[c], *(const bf16x8*)(bp + 32 + c * 32), acc, 0, 0, 0);
            acc4[jj] = acc;
        }
        float bs[4];
        #pragma unroll
        for (int jj = 0; jj < 4; ++jj) {
            const int o = head + 8 * (hidbase + jj);
            bs[jj] = (task == 0) ? kv_b_s[o] : ((o < 256) ? q_b_s[o] : kv_b_s[o]);
        }
        const int c = (hq & 7) ^ head;             // swizzle by (R>>4)&7 == head
        #pragma unroll
        for (int j = 0; j < 4; ++j) {
            const int R = region * 128 + head * 16 + lg * 4 + j;
            *(f32x4*)(OUTS + R * 32 + c * 4) =
                (f32x4){acc4[0][j] + bs[0], acc4[1][j] + bs[1],
                        acc4[2][j] + bs[2], acc4[3][j] + bs[3]};
        }
    }
    __syncthreads();

    {
        const int region = w >> 1;
        const size_t obase = task ? (region ? OFF_VSQ : OFF_QS)
                                  : (region ? OFF_VS  : OFF_KS);
        #pragma unroll
        for (int k = 0; k < 8; ++k) {
            const int head = (w & 1) * 4 + (k & 3);
            const int nl   = (k >> 2) * 8 + (l >> 3);
            const int q    = l & 7;
            f32x4 v = *(const f32x4*)(OUTS + ((region * 128 + head * 16 + nl)) * 32
                                      + ((q ^ head) & 7) * 4);
            __builtin_nontemporal_store(v,
                (f32x4*)(out + obase + (((size_t)(b * 8 + head)) * NN + n0 + nl) * 32
                         + q * 4));
        }
    }
}

extern "C" void kernel_launch(void* const* d_in, const int* in_sizes, int n_in,
                              void* d_out, int out_size, void* d_ws, size_t ws_size,
                              hipStream_t stream) {
    const float* inputs  = (const float*)d_in[0];
    const float* scalars = (const float*)d_in[1];
    const float* qwmv    = (const float*)d_in[2];
    const float* qws2mv  = (const float*)d_in[3];
    const float* qwmv2s  = (const float*)d_in[4];
    const float* qws2s   = (const float*)d_in[5];
    const float* qbs     = (const float*)d_in[6];
    const float* kvwmv   = (const float*)d_in[7];
    const float* kvws2mv = (const float*)d_in[8];
    const float* kvwmv2s = (const float*)d_in[9];
    const float* kvws2s  = (const float*)d_in[10];
    const float* kvbs    = (const float*)d_in[11];
    const int*   qidx    = (const int*)d_in[12];
    const int*   kvidx   = (const int*)d_in[13];
    short* ws   = (short*)d_ws;            // 11,026,432 B of scratch used
    float* outp = (float*)d_out;

    prep_all<<<2208, 256, 0, stream>>>(
        inputs, scalars, qwmv, qws2mv, qwmv2s, qws2s,
        kvwmv, kvws2mv, kvwmv2s, kvws2s, ws);

    // ABLATION (round 8): fused_all launched TWICE (idempotent — identical
    // stores both times). dur_round8 - dur_round7 ~= t(fused_all), isolating
    // the prep/fused split that rocprof top-5 cannot show (harness fills
    // dominate). Next round removes the duplicate and attacks whichever
    // component the measurement indicts.
    fused_all<<<1024, 256, 0, stream>>>(qbs, kvbs, qidx, kvidx, ws, outp);
    fused_all<<<1024, 256, 0, stream>>>(qbs, kvbs, qidx, kvidx, ws, outp);
}

// Round 9
// 49.541 us; speedup vs baseline: 2.1826x; 2.1826x over previous
//
#include <hip/hip_runtime.h>
#include <hip/hip_bf16.h>
#include <stdint.h>

typedef short bf16x8 __attribute__((ext_vector_type(8)));
typedef short bf16x2 __attribute__((ext_vector_type(2)));
typedef float f32x4 __attribute__((ext_vector_type(4)));

#define NN 4096

static __device__ __forceinline__ short f2b(float f) {
    union { float f; uint32_t u; } a; a.f = f;
    uint32_t r = a.u + 0x7FFFu + ((a.u >> 16) & 1u);
    return (short)(r >> 16);
}

// ---- output region offsets (in floats) ----
#define OFF_QMV   0UL
#define OFF_KMV   8388608UL
#define OFF_VMV   16777216UL
#define OFF_VMVQ  25165824UL
#define OFF_QS    33554432UL
#define OFF_KS    35651584UL
#define OFF_VS    37748736UL
#define OFF_VSQ   39845888UL

// ---- ws layout (bf16 elements) ----
// Bmv:   [task][y:9][ct:8][lane:64][e:8]    = 73728
// Bs2mv: [task][kk:4][ct:8][lane:64][e:8]   = 32768
// SW:    [task][ct:32][lr:16][k:160]        = 163840
#define WS_BMV_END   73728
#define WS_SW_BASE   106496
#define WS_PACK_END  270336    // shorts -> 540,672 bytes of scratch

// MV-GEMM column-channel map: (ct, lane) -> output channel O in [0,128)
static __device__ __forceinline__ int mv_chan(int ct, int l) {
    return (ct >> 2) * 64 + (l & 7) * 8 + (ct & 3) * 2 + ((l >> 3) & 1);
}

// col-channel mapping for the S GEMM: o(ct,lr) — bijective, bit-disjoint
static __device__ __forceinline__ int s_chan(int ct, int lr) {
    int hid = (ct & 3) + 4 * (lr >> 3) + 8 * (ct >> 2);
    return (lr & 7) + 8 * hid;
}

// ============ prep: weight fragment packs only ==============================
__global__ __launch_bounds__(256) void prep_pack(
    const float* __restrict__ qwmv,   const float* __restrict__ qws2mv,
    const float* __restrict__ qwmv2s, const float* __restrict__ qws2s,
    const float* __restrict__ kvwmv,  const float* __restrict__ kvws2mv,
    const float* __restrict__ kvwmv2s,const float* __restrict__ kvws2s,
    short* __restrict__ ws)
{
    const int id = blockIdx.x * 256 + threadIdx.x;
    if (id >= WS_PACK_END) return;
    float v;
    if (id < WS_BMV_END) {
        int rem = id; int task = rem / 36864; rem -= task * 36864;
        int y = rem / 4096; rem -= y * 4096;
        int ct = rem >> 9; int l = (rem >> 3) & 63; int e = rem & 7;
        int o = mv_chan(ct, l);
        int i = (l >> 4) * 8 + e;
        const float* w = (task == 0 || o >= 64) ? kvwmv : qwmv;
        v = w[(o * 32 + i) * 9 + y];
    } else if (id < WS_SW_BASE) {
        int rem = id - WS_BMV_END; int task = rem / 16384; rem -= task * 16384;
        int kk = rem / 4096; rem -= kk * 4096;
        int ct = rem >> 9; int l = (rem >> 3) & 63; int e = rem & 7;
        int o = mv_chan(ct, l);
        int k = kk * 32 + (l >> 4) * 8 + e;
        const float* w = (task == 0 || o >= 64) ? kvws2mv : qws2mv;
        v = w[o * 128 + k];
    } else {
        int rem = id - WS_SW_BASE; int task = rem / 81920; rem -= task * 81920;
        int ct = rem / 2560; rem -= ct * 2560;
        int lr = rem / 160;  int k = rem - lr * 160;
        int o = s_chan(ct, lr);
        if (k < 32) {
            const float* w = (task == 0 || o >= 256) ? kvwmv2s : qwmv2s;
            v = w[o * 32 + k];
        } else {
            const float* w = (task == 0 || o >= 256) ? kvws2s : qws2s;
            v = w[o * 128 + (k - 32)];
        }
    }
    ws[id] = f2b(v);
}

// ==== fused MV + S: fp32 gather + in-register f2b + LDS-transpose stores ====
__global__ __launch_bounds__(256) void fused_all(
    const float* __restrict__ inputs, const float* __restrict__ scalars,
    const float* __restrict__ q_b_s,  const float* __restrict__ kv_b_s,
    const int* __restrict__ q_idx,    const int* __restrict__ kv_idx,
    const short* __restrict__ ws,     float* __restrict__ out)
{
    const int GR[16]   = {0,1,1,1,1,2,2,2,2,2,2,3,3,3,3,4};
    const int SRC[16]  = {-1,0,-1,-1,-1,2,3,4,-1,-1,-1,8,9,10,-1,14};
    const int EMAP[16] = {0,5,0,0,0,6,6,6,0,0,0,7,7,7,0,8};

    __shared__ __align__(16) char SMEM[65536];
    short* XA = (short*)SMEM;            // [r:16][x:16][i:32], row stride 520
    short* XS = XA + 16 * 520;           // [r:16][k:128], stride 136

    const int tid  = threadIdx.x;
    const int bid  = blockIdx.x;
    const int tile = bid & 255;
    const int b    = (bid >> 8) & 1;
    const int task = bid >> 9;          // 0 = kv-task, 1 = q-task
    const int n0   = tile * 16;
    const int* ridx = task ? q_idx : kv_idx;

    // ---- staging: gather fp32 rows, convert in registers, write LDS ----
    {
        const int r = tid >> 4, c = tid & 15;
        const int m = ridx[n0 + r];
        const float* arow = inputs + (size_t)(b * NN + m) * 512;
        // XA: this thread covers i in {2c, 2c+1}, all 16 x
        short t2[2][16];
        #pragma unroll
        for (int ii = 0; ii < 2; ++ii)
            #pragma unroll
            for (int q = 0; q < 4; ++q) {
                const float4 v = *(const float4*)(arow + (2 * c + ii) * 16 + q * 4);
                t2[ii][q * 4 + 0] = f2b(v.x); t2[ii][q * 4 + 1] = f2b(v.y);
                t2[ii][q * 4 + 2] = f2b(v.z); t2[ii][q * 4 + 3] = f2b(v.w);
            }
        #pragma unroll
        for (int x = 0; x < 16; ++x) {
            bf16x2 pr = {t2[0][x], t2[1][x]};
            *(bf16x2*)(XA + r * 520 + x * 32 + 2 * c) = pr;   // b32, ~4-way worst
        }
        // XS: this thread covers k in [8c, 8c+8)
        const float* srow = scalars + (size_t)(b * NN + m) * 128 + c * 8;
        const float4 s0 = *(const float4*)(srow);
        const float4 s1 = *(const float4*)(srow + 4);
        bf16x8 sv = {f2b(s0.x), f2b(s0.y), f2b(s0.z), f2b(s0.w),
                     f2b(s1.x), f2b(s1.y), f2b(s1.z), f2b(s1.w)};
        *(bf16x8*)(XS + r * 136 + c * 8) = sv;                // b128, depth-8
    }
    __syncthreads();

    const int w  = tid >> 6;
    const int l  = tid & 63;
    const int lr = l & 15;
    const int lg = l >> 4;

    // ---- hoist all A fragments to registers (read LDS once) ----
    bf16x8 Ax[16];
    #pragma unroll
    for (int x = 0; x < 16; ++x)
        Ax[x] = *(const bf16x8*)(XA + lr * 520 + x * 32 + lg * 8);
    bf16x8 Sx[4];
    #pragma unroll
    for (int kk = 0; kk < 4; ++kk)
        Sx[kk] = *(const bf16x8*)(XS + lr * 136 + kk * 32 + lg * 8);
    __syncthreads();   // XA/XS dead; SMEM becomes per-wave mv-OUT buffers

    float* OUTw = (float*)SMEM + w * 4096;   // [row:32][128 floats], 16 KB/wave

    // ================= MV phase =================
    #pragma unroll
    for (int cc = 0; cc < 2; ++cc) {
        const int ct = 2 * w + cc;
        bf16x8 Bg[9];
        #pragma unroll
        for (int y = 0; y < 9; ++y)
            Bg[y] = *(const bf16x8*)(ws + ((((size_t)task * 9 + y) * 8 + ct) * 64 + l) * 8);

        #pragma unroll
        for (int xc = 0; xc < 4; ++xc) {
            f32x4 acc[4];
            #pragma unroll
            for (int q = 0; q < 4; ++q) {
                const int x = xc * 4 + q;
                f32x4 a0 = {0.f, 0.f, 0.f, 0.f};
                a0 = __builtin_amdgcn_mfma_f32_16x16x32_bf16(Ax[x], Bg[GR[x]], a0, 0, 0, 0);
                if (SRC[x] >= 0)
                    a0 = __builtin_amdgcn_mfma_f32_16x16x32_bf16(Ax[SRC[x]], Bg[EMAP[x]], a0, 0, 0, 0);
                if (x == 0) {
                    #pragma unroll
                    for (int kk = 0; kk < 4; ++kk) {
                        bf16x8 bs2 = *(const bf16x8*)(ws + WS_BMV_END +
                                       ((((size_t)task * 4 + kk) * 8 + ct) * 64 + l) * 8);
                        a0 = __builtin_amdgcn_mfma_f32_16x16x32_bf16(Sx[kk], bs2, a0, 0, 0, 0);
                    }
                }
                acc[q] = a0;
            }
            #pragma unroll
            for (int j = 0; j < 4; ++j) {
                const int roww = (lr >> 3) * 16 + lg * 4 + j;
                const int cqw  = ((lr & 7) * 4 + xc) ^ ((roww >> 2) & 7);
                *(f32x4*)(OUTw + roww * 128 + cqw * 4) =
                    (f32x4){acc[0][j], acc[1][j], acc[2][j], acc[3][j]};
            }
        }

        // readback + coalesced nontemporal store: 1 KB contiguous per instr
        const int region = ct >> 2;
        const size_t obase = task ? (region ? OFF_VMVQ : OFF_QMV)
                                  : (region ? OFF_VMV  : OFF_KMV);
        #pragma unroll
        for (int t = 0; t < 16; ++t) {
            const int row  = 2 * t + (l >> 5);
            const int h2   = row >> 4, nl = row & 15;
            const int head = (ct & 3) * 2 + h2;
            const int cq   = (l & 31) ^ ((row >> 2) & 7);
            f32x4 v = *(const f32x4*)(OUTw + row * 128 + cq * 4);
            __builtin_nontemporal_store(v,
                (f32x4*)(out + obase + (((size_t)(b * 8 + head)) * NN + n0 + nl) * 128
                         + (l & 31) * 4));
        }
    }

    // ================= S phase (reuses Ax[0], Sx in registers) =================
    __syncthreads();                       // mv-OUT dead in all waves
    float* OUTS = (float*)SMEM;            // [R:256][32 floats], 32 KB

    #pragma unroll
    for (int q8 = 0; q8 < 2; ++q8) {
        const int hidbase = 16 * w + 8 * q8 + 4 * (lr >> 3);
        const int head    = lr & 7;
        const int hq      = hidbase >> 2;          // global hid-quad
        const int region  = w >> 1;
        f32x4 acc4[4];
        #pragma unroll
        for (int jj = 0; jj < 4; ++jj) {
            const int ct = w * 8 + q8 * 4 + jj;
            const short* bp = ws + WS_SW_BASE +
                              (((size_t)task * 32 + ct) * 16 + lr) * 160 + lg * 8;
            f32x4 acc = {0.f, 0.f, 0.f, 0.f};
            acc = __builtin_amdgcn_mfma_f32_16x16x32_bf16(Ax[0], *(const bf16x8*)bp, acc, 0, 0, 0);
            #pragma unroll
            for (int c = 0; c < 4; ++c)
                acc = __builtin_amdgcn_mfma_f32_16x16x32_bf16(
                          Sx[c], *(const bf16x8*)(bp + 32 + c * 32), acc, 0, 0, 0);
            acc4[jj] = acc;
        }
        float bs[4];
        #pragma unroll
        for (int jj = 0; jj < 4; ++jj) {
            const int o = head + 8 * (hidbase + jj);
            bs[jj] = (task == 0) ? kv_b_s[o] : ((o < 256) ? q_b_s[o] : kv_b_s[o]);
        }
        const int c = (hq & 7) ^ head;             // swizzle by (R>>4)&7 == head
        #pragma unroll
        for (int j = 0; j < 4; ++j) {
            const int R = region * 128 + head * 16 + lg * 4 + j;
            *(f32x4*)(OUTS + R * 32 + c * 4) =
                (f32x4){acc4[0][j] + bs[0], acc4[1][j] + bs[1],
                        acc4[2][j] + bs[2], acc4[3][j] + bs[3]};
        }
    }
    __syncthreads();

    // readback + coalesced nontemporal store: 1 KB contiguous per instr
    {
        const int region = w >> 1;
        const size_t obase = task ? (region ? OFF_VSQ : OFF_QS)
                                  : (region ? OFF_VS  : OFF_KS);
        #pragma unroll
        for (int k = 0; k < 8; ++k) {
            const int head = (w & 1) * 4 + (k & 3);
            const int nl   = (k >> 2) * 8 + (l >> 3);
            const int q    = l & 7;
            f32x4 v = *(const f32x4*)(OUTS + ((region * 128 + head * 16 + nl)) * 32
                                      + ((q ^ head) & 7) * 4);
            __builtin_nontemporal_store(v,
                (f32x4*)(out + obase + (((size_t)(b * 8 + head)) * NN + n0 + nl) * 32
                         + q * 4));
        }
    }
}

extern "C" void kernel_launch(void* const* d_in, const int* in_sizes, int n_in,
                              void* d_out, int out_size, void* d_ws, size_t ws_size,
                              hipStream_t stream) {
    const float* inputs  = (const float*)d_in[0];
    const float* scalars = (const float*)d_in[1];
    const float* qwmv    = (const float*)d_in[2];
    const float* qws2mv  = (const float*)d_in[3];
    const float* qwmv2s  = (const float*)d_in[4];
    const float* qws2s   = (const float*)d_in[5];
    const float* qbs     = (const float*)d_in[6];
    const float* kvwmv   = (const float*)d_in[7];
    const float* kvws2mv = (const float*)d_in[8];
    const float* kvwmv2s = (const float*)d_in[9];
    const float* kvws2s  = (const float*)d_in[10];
    const float* kvbs    = (const float*)d_in[11];
    const int*   qidx    = (const int*)d_in[12];
    const int*   kvidx   = (const int*)d_in[13];
    short* ws   = (short*)d_ws;            // 540,672 B of scratch used
    float* outp = (float*)d_out;

    prep_pack<<<(WS_PACK_END + 255) / 256, 256, 0, stream>>>(
        qwmv, qws2mv, qwmv2s, qws2s, kvwmv, kvws2mv, kvwmv2s, kvws2s, ws);

    fused_all<<<1024, 256, 0, stream>>>(
        inputs, scalars, qbs, kvbs, qidx, kvidx, ws, outp);
}

// Round 10
// 46.513 us; speedup vs baseline: 2.3247x; 1.0651x over previous
//
#include <hip/hip_runtime.h>
#include <hip/hip_bf16.h>
#include <stdint.h>

typedef short bf16x8 __attribute__((ext_vector_type(8)));
typedef short bf16x4 __attribute__((ext_vector_type(4)));
typedef float f32x4 __attribute__((ext_vector_type(4)));

#define NN 4096

static __device__ __forceinline__ short f2b(float f) {
    union { float f; uint32_t u; } a; a.f = f;
    uint32_t r = a.u + 0x7FFFu + ((a.u >> 16) & 1u);
    return (short)(r >> 16);
}

// ---- output region offsets (in floats) ----
#define OFF_QMV   0UL
#define OFF_KMV   8388608UL
#define OFF_VMV   16777216UL
#define OFF_VMVQ  25165824UL
#define OFF_QS    33554432UL
#define OFF_KS    35651584UL
#define OFF_VS    37748736UL
#define OFF_VSQ   39845888UL

// ---- ws layout (bf16 elements) ----
// Bmv:   [task][y:9][ct:8][lane:64][e:8]    = 73728
// Bs2mv: [task][kk:4][ct:8][lane:64][e:8]   = 32768
// SW:    [task][ct:32][lr:16][k:160]        = 163840
#define WS_BMV_END   73728
#define WS_SW_BASE   106496
#define WS_PACK_END  270336    // shorts -> 540,672 bytes of scratch

// MV-GEMM column-channel map: (ct, lane) -> output channel O in [0,128)
static __device__ __forceinline__ int mv_chan(int ct, int l) {
    return (ct >> 2) * 64 + (l & 7) * 8 + (ct & 3) * 2 + ((l >> 3) & 1);
}

// col-channel mapping for the S GEMM: o(ct,lr) — bijective, bit-disjoint
static __device__ __forceinline__ int s_chan(int ct, int lr) {
    int hid = (ct & 3) + 4 * (lr >> 3) + 8 * (ct >> 2);
    return (lr & 7) + 8 * hid;
}

// ============ prep: weight fragment packs only ==============================
__global__ __launch_bounds__(256) void prep_pack(
    const float* __restrict__ qwmv,   const float* __restrict__ qws2mv,
    const float* __restrict__ qwmv2s, const float* __restrict__ qws2s,
    const float* __restrict__ kvwmv,  const float* __restrict__ kvws2mv,
    const float* __restrict__ kvwmv2s,const float* __restrict__ kvws2s,
    short* __restrict__ ws)
{
    const int id = blockIdx.x * 256 + threadIdx.x;
    if (id >= WS_PACK_END) return;
    float v;
    if (id < WS_BMV_END) {
        int rem = id; int task = rem / 36864; rem -= task * 36864;
        int y = rem / 4096; rem -= y * 4096;
        int ct = rem >> 9; int l = (rem >> 3) & 63; int e = rem & 7;
        int o = mv_chan(ct, l);
        int i = (l >> 4) * 8 + e;
        const float* w = (task == 0 || o >= 64) ? kvwmv : qwmv;
        v = w[(o * 32 + i) * 9 + y];
    } else if (id < WS_SW_BASE) {
        int rem = id - WS_BMV_END; int task = rem / 16384; rem -= task * 16384;
        int kk = rem / 4096; rem -= kk * 4096;
        int ct = rem >> 9; int l = (rem >> 3) & 63; int e = rem & 7;
        int o = mv_chan(ct, l);
        int k = kk * 32 + (l >> 4) * 8 + e;
        const float* w = (task == 0 || o >= 64) ? kvws2mv : qws2mv;
        v = w[o * 128 + k];
    } else {
        int rem = id - WS_SW_BASE; int task = rem / 81920; rem -= task * 81920;
        int ct = rem / 2560; rem -= ct * 2560;
        int lr = rem / 160;  int k = rem - lr * 160;
        int o = s_chan(ct, lr);
        if (k < 32) {
            const float* w = (task == 0 || o >= 256) ? kvwmv2s : qwmv2s;
            v = w[o * 32 + k];
        } else {
            const float* w = (task == 0 || o >= 256) ? kvws2s : qws2s;
            v = w[o * 128 + (k - 32)];
        }
    }
    ws[id] = f2b(v);
}

// ==== fused MV + S: 2-wave blocks, wave-private buffers, no post-hoist sync ====
__global__ __launch_bounds__(128) void fused_all(
    const float* __restrict__ inputs, const float* __restrict__ scalars,
    const float* __restrict__ q_b_s,  const float* __restrict__ kv_b_s,
    const int* __restrict__ q_idx,    const int* __restrict__ kv_idx,
    const short* __restrict__ ws,     float* __restrict__ out)
{
    const int GR[16]   = {0,1,1,1,1,2,2,2,2,2,2,3,3,3,3,4};
    const int SRC[16]  = {-1,0,-1,-1,-1,2,3,4,-1,-1,-1,8,9,10,-1,14};
    const int EMAP[16] = {0,5,0,0,0,6,6,6,0,0,0,7,7,7,0,8};

    __shared__ __align__(16) char SMEM[32768];
    short* XA = (short*)SMEM;            // [r:16][x:16][i:32], row stride 520
    short* XS = XA + 16 * 520;           // [r:16][k:128], stride 136

    const int tid  = threadIdx.x;
    const int bid  = blockIdx.x;
    const int tile = bid & 255;
    const int b    = (bid >> 8) & 1;
    const int task = bid >> 9;          // 0 = kv-task, 1 = q-task
    const int n0   = tile * 16;
    const int* ridx = task ? q_idx : kv_idx;

    // ---- staging: gather fp32 rows, convert in registers, write LDS ----
    {
        const int r = tid >> 3, c = tid & 7;    // 8 threads per row
        const int m = ridx[n0 + r];
        const float* arow = inputs + (size_t)(b * NN + m) * 512;
        // XA: this thread covers i in {4c..4c+3}, all 16 x
        short t4[4][16];
        #pragma unroll
        for (int ii = 0; ii < 4; ++ii)
            #pragma unroll
            for (int q = 0; q < 4; ++q) {
                const float4 v = *(const float4*)(arow + (4 * c + ii) * 16 + q * 4);
                t4[ii][q * 4 + 0] = f2b(v.x); t4[ii][q * 4 + 1] = f2b(v.y);
                t4[ii][q * 4 + 2] = f2b(v.z); t4[ii][q * 4 + 3] = f2b(v.w);
            }
        #pragma unroll
        for (int x = 0; x < 16; ++x) {
            bf16x4 pr = {t4[0][x], t4[1][x], t4[2][x], t4[3][x]};
            *(bf16x4*)(XA + r * 520 + x * 32 + 4 * c) = pr;   // b64
        }
        // XS: this thread covers k in [16c, 16c+16)
        const float* srow = scalars + (size_t)(b * NN + m) * 128 + c * 16;
        #pragma unroll
        for (int h = 0; h < 2; ++h) {
            const float4 s0 = *(const float4*)(srow + h * 8);
            const float4 s1 = *(const float4*)(srow + h * 8 + 4);
            bf16x8 sv = {f2b(s0.x), f2b(s0.y), f2b(s0.z), f2b(s0.w),
                         f2b(s1.x), f2b(s1.y), f2b(s1.z), f2b(s1.w)};
            *(bf16x8*)(XS + r * 136 + c * 16 + h * 8) = sv;
        }
    }
    __syncthreads();

    const int w  = tid >> 6;    // 2 waves
    const int l  = tid & 63;
    const int lr = l & 15;
    const int lg = l >> 4;

    // ---- hoist all A fragments to registers (read LDS once) ----
    bf16x8 Ax[16];
    #pragma unroll
    for (int x = 0; x < 16; ++x)
        Ax[x] = *(const bf16x8*)(XA + lr * 520 + x * 32 + lg * 8);
    bf16x8 Sx[4];
    #pragma unroll
    for (int kk = 0; kk < 4; ++kk)
        Sx[kk] = *(const bf16x8*)(XS + lr * 136 + kk * 32 + lg * 8);
    __syncthreads();   // last barrier: XA/XS dead, SMEM becomes per-wave OUT.
    // From here on, wave w only touches SMEM bytes [16384*w, 16384*(w+1)):
    // OUTw (mv) and its s-phase region are the SAME wave-private bytes, and
    // same-wave LDS ops are processed in order -> no further __syncthreads().

    float* OUTw = (float*)SMEM + w * 4096;   // [row:32][128 floats], 16 KB/wave

    // ================= MV phase: wave w handles ct in {4w..4w+3} =================
    #pragma unroll
    for (int cc = 0; cc < 4; ++cc) {
        const int ct = 4 * w + cc;
        bf16x8 Bg[9];
        #pragma unroll
        for (int y = 0; y < 9; ++y)
            Bg[y] = *(const bf16x8*)(ws + ((((size_t)task * 9 + y) * 8 + ct) * 64 + l) * 8);

        #pragma unroll
        for (int xc = 0; xc < 4; ++xc) {
            f32x4 acc[4];
            #pragma unroll
            for (int q = 0; q < 4; ++q) {
                const int x = xc * 4 + q;
                f32x4 a0 = {0.f, 0.f, 0.f, 0.f};
                a0 = __builtin_amdgcn_mfma_f32_16x16x32_bf16(Ax[x], Bg[GR[x]], a0, 0, 0, 0);
                if (SRC[x] >= 0)
                    a0 = __builtin_amdgcn_mfma_f32_16x16x32_bf16(Ax[SRC[x]], Bg[EMAP[x]], a0, 0, 0, 0);
                if (x == 0) {
                    #pragma unroll
                    for (int kk = 0; kk < 4; ++kk) {
                        bf16x8 bs2 = *(const bf16x8*)(ws + WS_BMV_END +
                                       ((((size_t)task * 4 + kk) * 8 + ct) * 64 + l) * 8);
                        a0 = __builtin_amdgcn_mfma_f32_16x16x32_bf16(Sx[kk], bs2, a0, 0, 0, 0);
                    }
                }
                acc[q] = a0;
            }
            #pragma unroll
            for (int j = 0; j < 4; ++j) {
                const int roww = (lr >> 3) * 16 + lg * 4 + j;
                const int cqw  = ((lr & 7) * 4 + xc) ^ ((roww >> 2) & 7);
                *(f32x4*)(OUTw + roww * 128 + cqw * 4) =
                    (f32x4){acc[0][j], acc[1][j], acc[2][j], acc[3][j]};
            }
        }

        // readback + coalesced nontemporal store: 1 KB contiguous per instr
        const int region = ct >> 2;
        const size_t obase = task ? (region ? OFF_VMVQ : OFF_QMV)
                                  : (region ? OFF_VMV  : OFF_KMV);
        #pragma unroll
        for (int t = 0; t < 16; ++t) {
            const int row  = 2 * t + (l >> 5);
            const int h2   = row >> 4, nl = row & 15;
            const int head = (ct & 3) * 2 + h2;
            const int cq   = (l & 31) ^ ((row >> 2) & 7);
            f32x4 v = *(const f32x4*)(OUTw + row * 128 + cq * 4);
            __builtin_nontemporal_store(v,
                (f32x4*)(out + obase + (((size_t)(b * 8 + head)) * NN + n0 + nl) * 128
                         + (l & 31) * 4));
        }
    }

    // ========== S phase: wave w handles ct in {16w..16w+15}, region = w ==========
    // OUTS rows [128w, 128w+128) == bytes [16384w, ...) == this wave's OUTw.
    float* OUTS = (float*)SMEM;            // [R:256][32 floats], 32 KB (wave-split)

    #pragma unroll
    for (int q8 = 0; q8 < 4; ++q8) {
        const int hidbase = 32 * w + 8 * q8 + 4 * (lr >> 3);
        const int head    = lr & 7;
        const int hq      = hidbase >> 2;          // global hid-quad
        f32x4 acc4[4];
        #pragma unroll
        for (int jj = 0; jj < 4; ++jj) {
            const int ct = w * 16 + q8 * 4 + jj;
            const short* bp = ws + WS_SW_BASE +
                              (((size_t)task * 32 + ct) * 16 + lr) * 160 + lg * 8;
            f32x4 acc = {0.f, 0.f, 0.f, 0.f};
            acc = __builtin_amdgcn_mfma_f32_16x16x32_bf16(Ax[0], *(const bf16x8*)bp, acc, 0, 0, 0);
            #pragma unroll
            for (int c = 0; c < 4; ++c)
                acc = __builtin_amdgcn_mfma_f32_16x16x32_bf16(
                          Sx[c], *(const bf16x8*)(bp + 32 + c * 32), acc, 0, 0, 0);
            acc4[jj] = acc;
        }
        float bs[4];
        #pragma unroll
        for (int jj = 0; jj < 4; ++jj) {
            const int o = head + 8 * (hidbase + jj);
            bs[jj] = (task == 0) ? kv_b_s[o] : ((o < 256) ? q_b_s[o] : kv_b_s[o]);
        }
        const int c = (hq & 7) ^ head;             // swizzle by (R>>4)&7 == head
        #pragma unroll
        for (int j = 0; j < 4; ++j) {
            const int R = w * 128 + head * 16 + lg * 4 + j;
            *(f32x4*)(OUTS + R * 32 + c * 4) =
                (f32x4){acc4[0][j] + bs[0], acc4[1][j] + bs[1],
                        acc4[2][j] + bs[2], acc4[3][j] + bs[3]};
        }
    }

    // readback + coalesced nontemporal store: 1 KB contiguous per instr
    {
        const size_t obase = task ? (w ? OFF_VSQ : OFF_QS)
                                  : (w ? OFF_VS  : OFF_KS);
        #pragma unroll
        for (int k = 0; k < 16; ++k) {
            const int head = k & 7;
            const int nl   = (k >> 3) * 8 + (l >> 3);
            const int q    = l & 7;
            f32x4 v = *(const f32x4*)(OUTS + ((w * 128 + head * 16 + nl)) * 32
                                      + ((q ^ head) & 7) * 4);
            __builtin_nontemporal_store(v,
                (f32x4*)(out + obase + (((size_t)(b * 8 + head)) * NN + n0 + nl) * 32
                         + q * 4));
        }
    }
}

extern "C" void kernel_launch(void* const* d_in, const int* in_sizes, int n_in,
                              void* d_out, int out_size, void* d_ws, size_t ws_size,
                              hipStream_t stream) {
    const float* inputs  = (const float*)d_in[0];
    const float* scalars = (const float*)d_in[1];
    const float* qwmv    = (const float*)d_in[2];
    const float* qws2mv  = (const float*)d_in[3];
    const float* qwmv2s  = (const float*)d_in[4];
    const float* qws2s   = (const float*)d_in[5];
    const float* qbs     = (const float*)d_in[6];
    const float* kvwmv   = (const float*)d_in[7];
    const float* kvws2mv = (const float*)d_in[8];
    const float* kvwmv2s = (const float*)d_in[9];
    const float* kvws2s  = (const float*)d_in[10];
    const float* kvbs    = (const float*)d_in[11];
    const int*   qidx    = (const int*)d_in[12];
    const int*   kvidx   = (const int*)d_in[13];
    short* ws   = (short*)d_ws;            // 540,672 B of scratch used
    float* outp = (float*)d_out;

    prep_pack<<<(WS_PACK_END + 255) / 256, 256, 0, stream>>>(
        qwmv, qws2mv, qwmv2s, qws2s, kvwmv, kvws2mv, kvwmv2s, kvws2s, ws);

    fused_all<<<1024, 128, 0, stream>>>(
        inputs, scalars, qbs, kvbs, qidx, kvidx, ws, outp);
}